// Round 4
// baseline (241.821 us; speedup 1.0000x reference)
//
#include <hip/hip_runtime.h>
#include <stdint.h>

typedef unsigned short u16;
typedef short short8 __attribute__((ext_vector_type(8)));
typedef float floatx4 __attribute__((ext_vector_type(4)));

#define B_N 32
#define CI  128
#define CO  256
#define HH  56
#define WW  56
#define HP  58
#define WP  58

// d_ws layout (bytes):
//   [0, 589824)      wb : bf16 w_eff, A-fragment order [k=rs*4+ic (36)][osub(16)][lane(64)][j(8)]
//   [590080, ...)    xp : bf16 [b(32)][h(58)][g=i/8(16)][w(58)][j=i%8(8)], borders zeroed
static const size_t XP_OFF = 590080;

__device__ __forceinline__ float bf2f(u16 u) {
  union { uint32_t i; float f; } c; c.i = ((uint32_t)u) << 16; return c.f;
}
__device__ __forceinline__ u16 f2bf(float f) {
  union { float f; uint32_t i; } c; c.f = f;
  uint32_t u = c.i;
  u += 0x7fffu + ((u >> 16) & 1u);   // round-to-nearest-even
  return (u16)(u >> 16);
}
__device__ __forceinline__ uint32_t pack2bf(float a, float b) {
  return (uint32_t)f2bf(a) | ((uint32_t)f2bf(b) << 16);
}

// ---- dtype probe, inlined per wave (uniform control flow required).
// bf16 inputs: ~64/64 plausible bf16 decodes of bias[0:64]; fp32: ~34/64.
__device__ __forceinline__ bool detect_bf16(const void* __restrict__ bias) {
  int lane = threadIdx.x & 63;
  float a = fabsf(bf2f(((const u16*)bias)[lane]));
  bool plausible = (a >= 1e-5f) && (a <= 0.5f);
  unsigned long long m = __ballot(plausible);
  return __popcll(m) >= 50;
}

// ---- w_eff[o,i,r,s] = rowsum[s] + colsum[r], stored so A-address is linear in k=rs*4+ic:
// elem (o,i,rs) -> ((k*16 + osub)*64 + lane)*8 + j,  osub=o>>4, lane=(i>>3&3)*16+(o&15), j=i&7
__global__ __launch_bounds__(256) void k_weff(const void* __restrict__ wsrc,
                                              u16* __restrict__ wb,
                                              const void* __restrict__ bias) {
  const bool isbf = detect_bf16(bias);
  int t = blockIdx.x * 256 + threadIdx.x;  // t = o*CI + i
  float v[9];
  if (isbf) {
    const u16* p = (const u16*)wsrc + (size_t)t * 9;
#pragma unroll
    for (int j = 0; j < 9; ++j) v[j] = bf2f(p[j]);
  } else {
    const float* p = (const float*)wsrc + (size_t)t * 9;
#pragma unroll
    for (int j = 0; j < 9; ++j) v[j] = p[j];
  }
  float rowsum[3] = { v[0]+v[1]+v[2], v[3]+v[4]+v[5], v[6]+v[7]+v[8] };
  float colsum[3] = { v[0]+v[3]+v[6], v[1]+v[4]+v[7], v[2]+v[5]+v[8] };
  const int o = t >> 7, i = t & 127;
  const int osub = o >> 4, lo = o & 15;
  const int ic = i >> 5, q = (i >> 3) & 3, j = i & 7;
#pragma unroll
  for (int r = 0; r < 3; ++r)
#pragma unroll
    for (int s = 0; s < 3; ++s) {
      int k = (r * 3 + s) * 4 + ic;
      wb[((size_t)(k * 16 + osub) * 64 + q * 16 + lo) * 8 + j] = f2bf(rowsum[s] + colsum[r]);
    }
}

// ---- x[b][i][h][w] -> xp[b][h+1][g][w+1][j] bf16; also writes all pad borders.
__global__ __launch_bounds__(256) void k_xpose(const void* __restrict__ xsrc,
                                               u16* __restrict__ xp,
                                               const void* __restrict__ bias) {
  __shared__ uint32_t tile32[CI * 29];  // [i][w-pair], stride 29 words (odd -> conflict-free)
  const int hp = blockIdx.x, b = blockIdx.y, tid = threadIdx.x;
  u16* dst = xp + (size_t)(b * HP + hp) * (16 * WP * 8);  // this pad-row block, 7424 u16
  if (hp == 0 || hp == HP - 1) {            // full zero row
    int4 z = {0, 0, 0, 0};
    for (int c = tid; c < 928; c += 256) *(int4*)(dst + c * 8) = z;
    return;
  }
  const bool isbf = detect_bf16(bias);
  const int h = hp - 1;
  if (isbf) {
    const uint32_t* xr = (const uint32_t*)xsrc;  // bf16 pairs, 28 words per (i,h) row
    for (int c = tid; c < CI * 28; c += 256) {
      int i = c / 28, wp = c - i * 28;
      tile32[i * 29 + wp] = xr[((size_t)(b * CI + i) * HH + h) * 28 + wp];
    }
  } else {
    const float4* xr = (const float4*)xsrc;      // 14 float4 per (i,h) row
    for (int c = tid; c < CI * 14; c += 256) {
      int i = c / 14, f4 = c - i * 14;
      float4 v = xr[((size_t)(b * CI + i) * HH + h) * 14 + f4];
      tile32[i * 29 + 2 * f4]     = pack2bf(v.x, v.y);
      tile32[i * 29 + 2 * f4 + 1] = pack2bf(v.z, v.w);
    }
  }
  __syncthreads();
  const u16* t16 = (const u16*)tile32;  // elem (i,w) at i*58 + w
  uint32_t* dw = (uint32_t*)dst;        // dest word (g, wpad, jj) at (g*58+wpad)*4+jj
  for (int c = tid; c < 16 * 56 * 4; c += 256) {
    int g = c / 224, rem = c - g * 224, w = rem >> 2, jj = rem & 3;
    int i0 = g * 8 + jj * 2;
    uint32_t lo16 = t16[i0 * 58 + w], hi16 = t16[(i0 + 1) * 58 + w];
    dw[(g * 58 + (w + 1)) * 4 + jj] = lo16 | (hi16 << 16);
  }
  if (tid < 128) {                      // col borders w=0 and w=57
    int g = tid >> 3, k = tid & 7, wb_ = (k >> 2) * 57, jj = k & 3;
    dw[(g * 58 + wb_) * 4 + jj] = 0;
  }
}

// ---- implicit-GEMM conv. Block (512 thr, 8 waves): ALL 256 o x 2 output rows
// (p0=2*pp). B-tile (pad rows p0..p0+3, 59.4 KB) staged ONCE in LDS ->
// barrier-free K-loop (36 steps, K=32) with ping-pong register double-buffering.
// waves: wm=wv&3 (o range wm*64..+63), wn=wv>>2 (output row p0+wn).
// 59.4 KB LDS x 2 blocks/CU = 119 KB -> 4 waves/SIMD for latency hiding.
#define ALOAD(DST, K)                                                            \
  {                                                                              \
    const u16* ap = wb + ((size_t)((K)*16 + osubbase) << 9) + lane * 8;          \
    DST##0 = *(const short8*)ap;                                                 \
    DST##1 = *(const short8*)(ap + 512);                                         \
    DST##2 = *(const short8*)(ap + 1024);                                        \
    DST##3 = *(const short8*)(ap + 1536);                                        \
  }
#define BLOAD(DST, K)                                                            \
  {                                                                              \
    int rs_ = (K) >> 2, ic_ = (K)&3;                                             \
    int r_ = (rs_ * 86) >> 8, s_ = rs_ - r_ * 3;                                 \
    const u16* bp = Bs + (((wn + r_) * 16 + ic_ * 4 + quad) * 58 + lo + s_) * 8; \
    DST##0 = *(const short8*)bp;                                                 \
    DST##1 = *(const short8*)(bp + 128);                                         \
    DST##2 = *(const short8*)(bp + 256);                                         \
    DST##3 = *(const short8*)(bp + 384);                                         \
  }
#define MSTEP(A, Bf)                                                                   \
  {                                                                                    \
    short8 am_[4] = {A##0, A##1, A##2, A##3};                                          \
    short8 bn_[4] = {Bf##0, Bf##1, Bf##2, Bf##3};                                      \
    _Pragma("unroll") for (int m = 0; m < 4; ++m)                                      \
        _Pragma("unroll") for (int n = 0; n < 4; ++n) acc[m][n] =                      \
            __builtin_amdgcn_mfma_f32_16x16x32_bf16(am_[m], bn_[n], acc[m][n], 0, 0, 0); \
  }

__global__ __launch_bounds__(512, 4) void k_gemm(const u16* __restrict__ wb,
                                                 const u16* __restrict__ xp,
                                                 const void* __restrict__ bias,
                                                 void* __restrict__ outv) {
  __shared__ u16 Bs[4 * 16 * 58 * 8 + 64];  // 4 pad rows + overread slack (masked cols)
  const int pp = blockIdx.x, b = blockIdx.y;
  const int p0 = 2 * pp;
  const int tid = threadIdx.x;
  const int wv = tid >> 6, lane = tid & 63;
  const int lo = lane & 15, quad = lane >> 4;
  const int wm = wv & 3, wn = wv >> 2;
  const int osubbase = wm * 4;

  // stage 4 pad rows (59392 B) of xp into LDS: contiguous 16 B per thread per iter
  {
    const u16* src = xp + (size_t)(b * HP + p0) * (16 * WP * 8);
    for (int c = tid; c < 3712; c += 512)
      *(int4*)(Bs + (size_t)c * 8) = *(const int4*)(src + (size_t)c * 8);
  }
  __syncthreads();

  floatx4 acc[4][4];
#pragma unroll
  for (int m = 0; m < 4; ++m)
#pragma unroll
    for (int n = 0; n < 4; ++n) acc[m][n] = (floatx4){0.f, 0.f, 0.f, 0.f};

  short8 a00, a01, a02, a03, a10, a11, a12, a13;
  short8 b00, b01, b02, b03, b10, b11, b12, b13;
  ALOAD(a0, 0); BLOAD(b0, 0);
#pragma unroll 1
  for (int k = 0; k < 36; k += 2) {
    ALOAD(a1, k + 1); BLOAD(b1, k + 1);   // prefetch odd step (k+1 <= 35 always)
    MSTEP(a0, b0);
    if (k + 2 < 36) { ALOAD(a0, k + 2); BLOAD(b0, k + 2); }
    MSTEP(a1, b1);
  }

  // epilogue: C/D layout col(q)=lane&15, row(o)=quad*4+reg
  const int prow = p0 + wn;
  const bool isbf = detect_bf16(bias);
  if (isbf) {
    u16* out = (u16*)outv;
    const u16* bs = (const u16*)bias;
#pragma unroll
    for (int m = 0; m < 4; ++m)
#pragma unroll
      for (int v = 0; v < 4; ++v) {
        const int o = wm * 64 + m * 16 + quad * 4 + v;
        const float bv = bf2f(bs[o]);
        size_t base = ((size_t)(b * CO + o) * HH + prow) * WW;
#pragma unroll
        for (int n = 0; n < 4; ++n) {
          const int q = n * 16 + lo;
          if (q < WW) out[base + q] = f2bf(acc[m][n][v] + bv);
        }
      }
  } else {
    float* out = (float*)outv;
    const float* bs = (const float*)bias;
#pragma unroll
    for (int m = 0; m < 4; ++m)
#pragma unroll
      for (int v = 0; v < 4; ++v) {
        const int o = wm * 64 + m * 16 + quad * 4 + v;
        const float bv = bs[o];
        size_t base = ((size_t)(b * CO + o) * HH + prow) * WW;
#pragma unroll
        for (int n = 0; n < 4; ++n) {
          const int q = n * 16 + lo;
          if (q < WW) out[base + q] = acc[m][n][v] + bv;
        }
      }
  }
}

extern "C" void kernel_launch(void* const* d_in, const int* in_sizes, int n_in,
                              void* d_out, int out_size, void* d_ws, size_t ws_size,
                              hipStream_t stream) {
  const void* x    = d_in[0];
  const void* w    = d_in[1];
  const void* bias = d_in[2];
  uint8_t* ws = (uint8_t*)d_ws;
  u16* wb = (u16*)ws;
  u16* xp = (u16*)(ws + XP_OFF);

  k_weff<<<dim3((CO * CI) / 256), 256, 0, stream>>>(w, wb, bias);
  k_xpose<<<dim3(HP, B_N), 256, 0, stream>>>(x, xp, bias);
  k_gemm<<<dim3(28, B_N), 512, 0, stream>>>(wb, xp, bias, d_out);
}

// Round 5
// 213.150 us; speedup vs baseline: 1.1345x; 1.1345x over previous
//
#include <hip/hip_runtime.h>
#include <stdint.h>

typedef unsigned short u16;
typedef short short8 __attribute__((ext_vector_type(8)));
typedef float floatx4 __attribute__((ext_vector_type(4)));

#define B_N 32
#define CI  128
#define CO  256
#define HH  56
#define WW  56
#define HP  58
#define WP  58

// d_ws layout (bytes):
//   [0, 589824)      wb : bf16 w_eff, A-fragment order [k=rs*4+ic (36)][osub(16)][lane(64)][j(8)]
//   [590080, ...)    xp : bf16 [b(32)][h(58)][g=i/8(16)][w(58)][j=i%8(8)], borders zeroed
static const size_t XP_OFF = 590080;

__device__ __forceinline__ float bf2f(u16 u) {
  union { uint32_t i; float f; } c; c.i = ((uint32_t)u) << 16; return c.f;
}
__device__ __forceinline__ u16 f2bf(float f) {
  union { float f; uint32_t i; } c; c.f = f;
  uint32_t u = c.i;
  u += 0x7fffu + ((u >> 16) & 1u);   // round-to-nearest-even
  return (u16)(u >> 16);
}
__device__ __forceinline__ uint32_t pack2bf(float a, float b) {
  return (uint32_t)f2bf(a) | ((uint32_t)f2bf(b) << 16);
}

// ---- dtype probe, inlined per wave (uniform control flow required).
// bf16 inputs: ~64/64 plausible bf16 decodes of bias[0:64]; fp32: ~34/64.
__device__ __forceinline__ bool detect_bf16(const void* __restrict__ bias) {
  int lane = threadIdx.x & 63;
  float a = fabsf(bf2f(((const u16*)bias)[lane]));
  bool plausible = (a >= 1e-5f) && (a <= 0.5f);
  unsigned long long m = __ballot(plausible);
  return __popcll(m) >= 50;
}

// ---- fused prep kernel, grid (59, 32):
//  hp < 58 : x[b][i][h][w] -> xp[b][hp][g][w][j] bf16 (incl. all pad borders)
//  hp == 58: w_eff build for chunk-set b (4 chunks of 256 (o,i) pairs each)
//            w_eff[o,i,r,s] = rowsum[s] + colsum[r]; stored A-fragment order:
//            elem (o,i,k=rs*4+ic) -> ((k*16+osub)*64 + (iq*16 + o&15))*8 + (i&7)
__global__ __launch_bounds__(256) void k_prep(const void* __restrict__ xsrc,
                                              const void* __restrict__ wsrc,
                                              u16* __restrict__ xp,
                                              u16* __restrict__ wb,
                                              const void* __restrict__ bias) {
  const int hp = blockIdx.x, b = blockIdx.y, tid = threadIdx.x;
  if (hp == HP) {  // ---- weff role
    const bool isbf = detect_bf16(bias);
#pragma unroll 1
    for (int sub = 0; sub < 4; ++sub) {
      int t = (b * 4 + sub) * 256 + tid;  // t = o*CI + i
      float v[9];
      if (isbf) {
        const u16* p = (const u16*)wsrc + (size_t)t * 9;
#pragma unroll
        for (int j = 0; j < 9; ++j) v[j] = bf2f(p[j]);
      } else {
        const float* p = (const float*)wsrc + (size_t)t * 9;
#pragma unroll
        for (int j = 0; j < 9; ++j) v[j] = p[j];
      }
      float rowsum[3] = { v[0]+v[1]+v[2], v[3]+v[4]+v[5], v[6]+v[7]+v[8] };
      float colsum[3] = { v[0]+v[3]+v[6], v[1]+v[4]+v[7], v[2]+v[5]+v[8] };
      const int o = t >> 7, i = t & 127;
      const int osub = o >> 4, lo = o & 15;
      const int ic = i >> 5, q = (i >> 3) & 3, j = i & 7;
#pragma unroll
      for (int r = 0; r < 3; ++r)
#pragma unroll
        for (int s = 0; s < 3; ++s) {
          int k = (r * 3 + s) * 4 + ic;
          wb[((size_t)(k * 16 + osub) * 64 + q * 16 + lo) * 8 + j] = f2bf(rowsum[s] + colsum[r]);
        }
    }
    return;
  }
  // ---- xpose role
  __shared__ uint32_t tile32[CI * 29];  // [i][w-pair], stride 29 words (conflict-free)
  u16* dst = xp + (size_t)(b * HP + hp) * (16 * WP * 8);  // this pad-row block, 7424 u16
  if (hp == 0 || hp == HP - 1) {            // full zero row
    int4 z = {0, 0, 0, 0};
    for (int c = tid; c < 928; c += 256) *(int4*)(dst + c * 8) = z;
    return;
  }
  const bool isbf = detect_bf16(bias);
  const int h = hp - 1;
  if (isbf) {
    const uint32_t* xr = (const uint32_t*)xsrc;  // bf16 pairs, 28 words per (i,h) row
    for (int c = tid; c < CI * 28; c += 256) {
      int i = c / 28, wp = c - i * 28;
      tile32[i * 29 + wp] = xr[((size_t)(b * CI + i) * HH + h) * 28 + wp];
    }
  } else {
    const float4* xr = (const float4*)xsrc;      // 14 float4 per (i,h) row
    for (int c = tid; c < CI * 14; c += 256) {
      int i = c / 14, f4 = c - i * 14;
      float4 v = xr[((size_t)(b * CI + i) * HH + h) * 14 + f4];
      tile32[i * 29 + 2 * f4]     = pack2bf(v.x, v.y);
      tile32[i * 29 + 2 * f4 + 1] = pack2bf(v.z, v.w);
    }
  }
  __syncthreads();
  const u16* t16 = (const u16*)tile32;  // elem (i,w) at i*58 + w
  uint32_t* dw = (uint32_t*)dst;        // dest word (g, wpad, jj) at (g*58+wpad)*4+jj
  for (int c = tid; c < 16 * 56 * 4; c += 256) {
    int g = c / 224, rem = c - g * 224, w = rem >> 2, jj = rem & 3;
    int i0 = g * 8 + jj * 2;
    uint32_t lo16 = t16[i0 * 58 + w], hi16 = t16[(i0 + 1) * 58 + w];
    dw[(g * 58 + (w + 1)) * 4 + jj] = lo16 | (hi16 << 16);
  }
  if (tid < 128) {                      // col borders w=0 and w=57
    int g = tid >> 3, k = tid & 7, wb_ = (k >> 2) * 57, jj = k & 3;
    dw[(g * 58 + wb_) * 4 + jj] = 0;
  }
}

// ---- implicit-GEMM conv. Block (256 thr, 4 waves): ALL 256 o x ONE output row p.
// B-tile (pad rows p..p+2, 44.8 KB LDS) staged once -> barrier-free K-loop (36 steps,
// K=32) with ping-pong register double-buffering. wave wv = wm (o range wm*64..+63).
// 44.8 KB x 3 blocks/CU -> 3 waves/SIMD; regs ~88 VGPR + 64 AGPR = 152 <= 170 cap.
#define ALOAD(DST, K)                                                            \
  {                                                                              \
    const u16* ap = wb + ((size_t)((K)*16 + osubbase) << 9) + lane * 8;          \
    DST##0 = *(const short8*)ap;                                                 \
    DST##1 = *(const short8*)(ap + 512);                                         \
    DST##2 = *(const short8*)(ap + 1024);                                        \
    DST##3 = *(const short8*)(ap + 1536);                                        \
  }
#define BLOAD(DST, K)                                                            \
  {                                                                              \
    int rs_ = (K) >> 2, ic_ = (K)&3;                                             \
    int r_ = (rs_ * 86) >> 8, s_ = rs_ - r_ * 3;                                 \
    const u16* bp = Bs + (((r_ * 16 + ic_ * 4 + quad) * 58) + lo + s_) * 8;      \
    DST##0 = *(const short8*)bp;                                                 \
    DST##1 = *(const short8*)(bp + 128);                                         \
    DST##2 = *(const short8*)(bp + 256);                                         \
    DST##3 = *(const short8*)(bp + 384);                                         \
  }
#define MSTEP(A, Bf)                                                                   \
  {                                                                                    \
    short8 am_[4] = {A##0, A##1, A##2, A##3};                                          \
    short8 bn_[4] = {Bf##0, Bf##1, Bf##2, Bf##3};                                      \
    _Pragma("unroll") for (int m = 0; m < 4; ++m)                                      \
        _Pragma("unroll") for (int n = 0; n < 4; ++n) acc[m][n] =                      \
            __builtin_amdgcn_mfma_f32_16x16x32_bf16(am_[m], bn_[n], acc[m][n], 0, 0, 0); \
  }

__global__ __launch_bounds__(256, 3) void k_gemm(const u16* __restrict__ wb,
                                                 const u16* __restrict__ xp,
                                                 const void* __restrict__ bias,
                                                 void* __restrict__ outv) {
  __shared__ u16 Bs[3 * 16 * 58 * 8 + 128];  // 3 pad rows + overread slack (masked cols)
  const int p = blockIdx.x, b = blockIdx.y;
  const int tid = threadIdx.x;
  const int wv = tid >> 6, lane = tid & 63;
  const int lo = lane & 15, quad = lane >> 4;
  const int wm = wv;
  const int osubbase = wm * 4;

  // stage 3 pad rows (44544 B) of xp into LDS: contiguous 16 B per thread per iter
  {
    const u16* src = xp + (size_t)(b * HP + p) * (16 * WP * 8);
    for (int c = tid; c < 2784; c += 256)
      *(int4*)(Bs + (size_t)c * 8) = *(const int4*)(src + (size_t)c * 8);
  }
  __syncthreads();

  floatx4 acc[4][4];
#pragma unroll
  for (int m = 0; m < 4; ++m)
#pragma unroll
    for (int n = 0; n < 4; ++n) acc[m][n] = (floatx4){0.f, 0.f, 0.f, 0.f};

  short8 a00, a01, a02, a03, a10, a11, a12, a13;
  short8 b00, b01, b02, b03, b10, b11, b12, b13;
  ALOAD(a0, 0); BLOAD(b0, 0);
#pragma unroll 1
  for (int k = 0; k < 36; k += 2) {
    ALOAD(a1, k + 1); BLOAD(b1, k + 1);   // prefetch odd step (k+1 <= 35 always)
    MSTEP(a0, b0);
    if (k + 2 < 36) { ALOAD(a0, k + 2); BLOAD(b0, k + 2); }
    MSTEP(a1, b1);
  }

  // epilogue: C/D layout col(q)=lane&15, row(o)=quad*4+reg
  const bool isbf = detect_bf16(bias);
  if (isbf) {
    u16* out = (u16*)outv;
    const u16* bs = (const u16*)bias;
#pragma unroll
    for (int m = 0; m < 4; ++m)
#pragma unroll
      for (int v = 0; v < 4; ++v) {
        const int o = wm * 64 + m * 16 + quad * 4 + v;
        const float bv = bf2f(bs[o]);
        size_t base = ((size_t)(b * CO + o) * HH + p) * WW;
#pragma unroll
        for (int n = 0; n < 4; ++n) {
          const int q = n * 16 + lo;
          if (q < WW) out[base + q] = f2bf(acc[m][n][v] + bv);
        }
      }
  } else {
    float* out = (float*)outv;
    const float* bs = (const float*)bias;
#pragma unroll
    for (int m = 0; m < 4; ++m)
#pragma unroll
      for (int v = 0; v < 4; ++v) {
        const int o = wm * 64 + m * 16 + quad * 4 + v;
        const float bv = bs[o];
        size_t base = ((size_t)(b * CO + o) * HH + p) * WW;
#pragma unroll
        for (int n = 0; n < 4; ++n) {
          const int q = n * 16 + lo;
          if (q < WW) out[base + q] = acc[m][n][v] + bv;
        }
      }
  }
}

extern "C" void kernel_launch(void* const* d_in, const int* in_sizes, int n_in,
                              void* d_out, int out_size, void* d_ws, size_t ws_size,
                              hipStream_t stream) {
  const void* x    = d_in[0];
  const void* w    = d_in[1];
  const void* bias = d_in[2];
  uint8_t* ws = (uint8_t*)d_ws;
  u16* wb = (u16*)ws;
  u16* xp = (u16*)(ws + XP_OFF);

  k_prep<<<dim3(HP + 1, B_N), 256, 0, stream>>>(x, w, xp, wb, bias);
  k_gemm<<<dim3(HH, B_N), 256, 0, stream>>>(wb, xp, bias, d_out);
}

// Round 6
// 202.318 us; speedup vs baseline: 1.1953x; 1.0535x over previous
//
#include <hip/hip_runtime.h>
#include <stdint.h>

typedef unsigned short u16;
typedef short short8 __attribute__((ext_vector_type(8)));
typedef float floatx4 __attribute__((ext_vector_type(4)));

#define B_N 32
#define CI  128
#define CO  256
#define HH  56
#define WW  56
#define HP  58
#define WP  58

// d_ws layout (bytes):
//   [0, 589824)      wb : bf16 w_eff, A-fragment order [k=rs*4+ic (36)][osub(16)][lane(64)][j(8)]
//   [590080, ...)    xp : bf16 [b(32)][h(58)][g=i/8(16)][w(58)][j=i%8(8)], borders zeroed
static const size_t XP_OFF = 590080;

__device__ __forceinline__ float bf2f(u16 u) {
  union { uint32_t i; float f; } c; c.i = ((uint32_t)u) << 16; return c.f;
}
__device__ __forceinline__ u16 f2bf(float f) {
  union { float f; uint32_t i; } c; c.f = f;
  uint32_t u = c.i;
  u += 0x7fffu + ((u >> 16) & 1u);   // round-to-nearest-even
  return (u16)(u >> 16);
}
__device__ __forceinline__ uint32_t pack2bf(float a, float b) {
  return (uint32_t)f2bf(a) | ((uint32_t)f2bf(b) << 16);
}

// ---- dtype probe, inlined per wave (uniform control flow required).
// bf16 inputs: ~64/64 plausible bf16 decodes of bias[0:64]; fp32: ~34/64.
__device__ __forceinline__ bool detect_bf16(const void* __restrict__ bias) {
  int lane = threadIdx.x & 63;
  float a = fabsf(bf2f(((const u16*)bias)[lane]));
  bool plausible = (a >= 1e-5f) && (a <= 0.5f);
  unsigned long long m = __ballot(plausible);
  return __popcll(m) >= 50;
}

// ---- fused prep kernel, grid (59, 32):
//  hp < 58 : x[b][i][h][w] -> xp[b][hp][g][w][j] bf16 (incl. all pad borders)
//  hp == 58: w_eff build for chunk-set b; w_eff[o,i,r,s] = rowsum[s] + colsum[r],
//            stored A-fragment order (see wb layout above).
__global__ __launch_bounds__(256) void k_prep(const void* __restrict__ xsrc,
                                              const void* __restrict__ wsrc,
                                              u16* __restrict__ xp,
                                              u16* __restrict__ wb,
                                              const void* __restrict__ bias) {
  const int hp = blockIdx.x, b = blockIdx.y, tid = threadIdx.x;
  if (hp == HP) {  // ---- weff role
    const bool isbf = detect_bf16(bias);
#pragma unroll 1
    for (int sub = 0; sub < 4; ++sub) {
      int t = (b * 4 + sub) * 256 + tid;  // t = o*CI + i
      float v[9];
      if (isbf) {
        const u16* p = (const u16*)wsrc + (size_t)t * 9;
#pragma unroll
        for (int j = 0; j < 9; ++j) v[j] = bf2f(p[j]);
      } else {
        const float* p = (const float*)wsrc + (size_t)t * 9;
#pragma unroll
        for (int j = 0; j < 9; ++j) v[j] = p[j];
      }
      float rowsum[3] = { v[0]+v[1]+v[2], v[3]+v[4]+v[5], v[6]+v[7]+v[8] };
      float colsum[3] = { v[0]+v[3]+v[6], v[1]+v[4]+v[7], v[2]+v[5]+v[8] };
      const int o = t >> 7, i = t & 127;
      const int osub = o >> 4, lo = o & 15;
      const int ic = i >> 5, q = (i >> 3) & 3, j = i & 7;
#pragma unroll
      for (int r = 0; r < 3; ++r)
#pragma unroll
        for (int s = 0; s < 3; ++s) {
          int k = (r * 3 + s) * 4 + ic;
          wb[((size_t)(k * 16 + osub) * 64 + q * 16 + lo) * 8 + j] = f2bf(rowsum[s] + colsum[r]);
        }
    }
    return;
  }
  // ---- xpose role
  __shared__ uint32_t tile32[CI * 29];  // [i][w-pair], stride 29 words (conflict-free)
  u16* dst = xp + (size_t)(b * HP + hp) * (16 * WP * 8);  // this pad-row block, 7424 u16
  if (hp == 0 || hp == HP - 1) {            // full zero row
    int4 z = {0, 0, 0, 0};
    for (int c = tid; c < 928; c += 256) *(int4*)(dst + c * 8) = z;
    return;
  }
  const bool isbf = detect_bf16(bias);
  const int h = hp - 1;
  if (isbf) {
    const uint32_t* xr = (const uint32_t*)xsrc;  // bf16 pairs, 28 words per (i,h) row
    for (int c = tid; c < CI * 28; c += 256) {
      int i = c / 28, wp = c - i * 28;
      tile32[i * 29 + wp] = xr[((size_t)(b * CI + i) * HH + h) * 28 + wp];
    }
  } else {
    const float4* xr = (const float4*)xsrc;      // 14 float4 per (i,h) row
    for (int c = tid; c < CI * 14; c += 256) {
      int i = c / 14, f4 = c - i * 14;
      float4 v = xr[((size_t)(b * CI + i) * HH + h) * 14 + f4];
      tile32[i * 29 + 2 * f4]     = pack2bf(v.x, v.y);
      tile32[i * 29 + 2 * f4 + 1] = pack2bf(v.z, v.w);
    }
  }
  __syncthreads();
  const u16* t16 = (const u16*)tile32;  // elem (i,w) at i*58 + w
  uint32_t* dw = (uint32_t*)dst;        // dest word (g, wpad, jj) at (g*58+wpad)*4+jj
  for (int c = tid; c < 16 * 56 * 4; c += 256) {
    int g = c / 224, rem = c - g * 224, w = rem >> 2, jj = rem & 3;
    int i0 = g * 8 + jj * 2;
    uint32_t lo16 = t16[i0 * 58 + w], hi16 = t16[(i0 + 1) * 58 + w];
    dw[(g * 58 + (w + 1)) * 4 + jj] = lo16 | (hi16 << 16);
  }
  if (tid < 128) {                      // col borders w=0 and w=57
    int g = tid >> 3, k = tid & 7, wb_ = (k >> 2) * 57, jj = k & 3;
    dw[(g * 58 + wb_) * 4 + jj] = 0;
  }
}

// ---- implicit-GEMM conv. Block (256 thr, 4 waves): 256 o x TWO output rows
// (p0 = 2*blockIdx.x). Wave wv: M=64 (o-quarter wv), N=128 = 2 rows x 64 cols
// (cols >=56 masked) -> A-traffic per CU halves vs N=64 waves (the round-5 binder:
// per-CU VMEM A-stream ~50 GB/s/CU). B: 4 pad rows in LDS, g-row stride padded
// 58->59 chunks (=472 u16, 236 words, != 8 mod 32) to cut bank conflicts.
// Ping-pong double-buffering of A (global/L2) and B (ds_read_b128) fragments.
// ~240 regs/wave -> 2 waves/SIMD; LDS 60.4 KB -> 2 blocks/CU.
#define GSTRIDE 472          // u16 per g-row in LDS (59 chunks of 8)
#define RSTRIDE (16 * 472)   // u16 per pad-row tensor in LDS

#define ALOAD(BUF, K)                                                       \
  {                                                                         \
    const u16* ap = wb + ((size_t)((K)*16 + osubbase) << 9) + lane * 8;     \
    af[BUF][0] = *(const short8*)ap;                                        \
    af[BUF][1] = *(const short8*)(ap + 512);                                \
    af[BUF][2] = *(const short8*)(ap + 1024);                               \
    af[BUF][3] = *(const short8*)(ap + 1536);                               \
  }
#define BLOAD(BUF, K)                                                       \
  {                                                                         \
    int rs_ = (K) >> 2, ic_ = (K)&3;                                        \
    int r_ = (rs_ * 86) >> 8, s_ = rs_ - r_ * 3;                            \
    const u16* bp = Bs + ((r_ * 16 + ic_ * 4 + quad) * GSTRIDE) + (lo + s_) * 8; \
    bfr[BUF][0] = *(const short8*)bp;                                       \
    bfr[BUF][1] = *(const short8*)(bp + 128);                               \
    bfr[BUF][2] = *(const short8*)(bp + 256);                               \
    bfr[BUF][3] = *(const short8*)(bp + 384);                               \
    bfr[BUF][4] = *(const short8*)(bp + RSTRIDE);                           \
    bfr[BUF][5] = *(const short8*)(bp + RSTRIDE + 128);                     \
    bfr[BUF][6] = *(const short8*)(bp + RSTRIDE + 256);                     \
    bfr[BUF][7] = *(const short8*)(bp + RSTRIDE + 384);                     \
  }
#define MSTEP(BUF)                                                          \
  _Pragma("unroll") for (int m = 0; m < 4; ++m)                             \
      _Pragma("unroll") for (int n = 0; n < 8; ++n) acc[m][n] =             \
          __builtin_amdgcn_mfma_f32_16x16x32_bf16(af[BUF][m], bfr[BUF][n],  \
                                                  acc[m][n], 0, 0, 0);

__global__ __launch_bounds__(256, 2) void k_gemm(const u16* __restrict__ wb,
                                                 const u16* __restrict__ xp,
                                                 const void* __restrict__ bias,
                                                 void* __restrict__ outv) {
  __shared__ u16 Bs[4 * RSTRIDE + 64];  // 4 pad-row tensors + overread slack
  const int p0 = 2 * blockIdx.x, b = blockIdx.y;
  const int tid = threadIdx.x;
  const int wv = tid >> 6, lane = tid & 63;
  const int lo = lane & 15, quad = lane >> 4;
  const int osubbase = wv * 4;

  // stage 4 pad rows of xp into LDS with g-row padding 58->59 chunks
  {
    const u16* src = xp + (size_t)(b * HP + p0) * (16 * WP * 8);
    for (int c = tid; c < 3712; c += 256) {
      int row = c / 928, rem = c - row * 928;
      int g = rem / 58, w = rem - g * 58;
      *(int4*)(Bs + (size_t)((row * 16 + g) * 59 + w) * 8) = *(const int4*)(src + (size_t)c * 8);
    }
  }
  __syncthreads();

  floatx4 acc[4][8];
#pragma unroll
  for (int m = 0; m < 4; ++m)
#pragma unroll
    for (int n = 0; n < 8; ++n) acc[m][n] = (floatx4){0.f, 0.f, 0.f, 0.f};

  short8 af[2][4], bfr[2][8];
  ALOAD(0, 0); BLOAD(0, 0);
#pragma unroll 1
  for (int k = 0; k < 36; k += 2) {
    ALOAD(1, k + 1); BLOAD(1, k + 1);   // prefetch odd step (k+1 <= 35 always)
    MSTEP(0);
    if (k + 2 < 36) { ALOAD(0, k + 2); BLOAD(0, k + 2); }
    MSTEP(1);
  }

  // epilogue: C/D layout col(q)=lane&15, row(o)=quad*4+reg; n-tile: row p0+(n>>2),
  // cols (n&3)*16+lo (masked >=56)
  const bool isbf = detect_bf16(bias);
  if (isbf) {
    u16* out = (u16*)outv;
    const u16* bs = (const u16*)bias;
#pragma unroll
    for (int m = 0; m < 4; ++m)
#pragma unroll
      for (int v = 0; v < 4; ++v) {
        const int o = wv * 64 + m * 16 + quad * 4 + v;
        const float bv = bf2f(bs[o]);
        size_t base = ((size_t)(b * CO + o) * HH + p0) * WW;
#pragma unroll
        for (int n = 0; n < 8; ++n) {
          const int q = (n & 3) * 16 + lo;
          if (q < WW) out[base + (n >> 2) * WW + q] = f2bf(acc[m][n][v] + bv);
        }
      }
  } else {
    float* out = (float*)outv;
    const float* bs = (const float*)bias;
#pragma unroll
    for (int m = 0; m < 4; ++m)
#pragma unroll
      for (int v = 0; v < 4; ++v) {
        const int o = wv * 64 + m * 16 + quad * 4 + v;
        const float bv = bs[o];
        size_t base = ((size_t)(b * CO + o) * HH + p0) * WW;
#pragma unroll
        for (int n = 0; n < 8; ++n) {
          const int q = (n & 3) * 16 + lo;
          if (q < WW) out[base + (n >> 2) * WW + q] = acc[m][n][v] + bv;
        }
      }
  }
}

extern "C" void kernel_launch(void* const* d_in, const int* in_sizes, int n_in,
                              void* d_out, int out_size, void* d_ws, size_t ws_size,
                              hipStream_t stream) {
  const void* x    = d_in[0];
  const void* w    = d_in[1];
  const void* bias = d_in[2];
  uint8_t* ws = (uint8_t*)d_ws;
  u16* wb = (u16*)ws;
  u16* xp = (u16*)(ws + XP_OFF);

  k_prep<<<dim3(HP + 1, B_N), 256, 0, stream>>>(x, w, xp, wb, bias);
  k_gemm<<<dim3(HH / 2, B_N), 256, 0, stream>>>(wb, xp, bias, d_out);
}